// Round 7
// baseline (3033.579 us; speedup 1.0000x reference)
//
#include <hip/hip_runtime.h>
#include <hip/hip_bf16.h>

// LSTM: T=512, B=64, H=512, L=2.  inputs: x[T,B,H] f32, Wh[L,H,4H], Wx[L,H,4H], bh[L,4H]
// out = concat(out[T,B,H], h_fin[L,B,H], c_fin[L,B,H]) f32.
//
// R7: depth-3 pipeline. 256 WGs = 2 layers x 32 col-strips x 4 row-quads.
// Stage s: layer0 computes t=s, layer1 computes t=s-2 (one stage of slack on
// the h0->L1 edge). Per stage, each layer's NON-critical operand (xq for L0,
// h0[t] for L1) is staged and its 8 Wx-MFMAs computed BEFORE the self-flag
// poll; only the self-recurrence h (16KB sc1) + 8 Wh-MFMAs + gates + publish
// remain on the inter-stage critical chain. All cross-WG data via sc1
// (MALL-coherent, never flushes L2); weights/xq stay normal cached loads.

#define TSEQ 512
#define BATCH 64
#define HID 512
#define H4 2048
#define BH (BATCH * HID)
#define DEPTH 8
#define ZSLOT DEPTH
#define QR 16            // batch rows per quad

typedef short bf16x8 __attribute__((ext_vector_type(8)));
typedef float f32x4 __attribute__((ext_vector_type(4)));
typedef float f32x2 __attribute__((ext_vector_type(2)));
typedef unsigned long long u64;

__device__ __forceinline__ ushort f32_to_bf16(float f) {
    unsigned u = __builtin_bit_cast(unsigned, f);
    u += 0x7FFFu + ((u >> 16) & 1u);   // round-to-nearest-even
    return (ushort)(u >> 16);
}

// 16B agent-coherent load (bypasses L1/L2, serviced at MALL)
__device__ __forceinline__ bf16x8 load16_sc1(const ushort* p) {
    bf16x8 v;
    asm volatile("global_load_dwordx4 %0, %1, off sc1" : "=v"(v) : "v"(p));
    return v;
}

// ---- convert x f32 -> bf16 (vectorized) ----
__global__ __launch_bounds__(256) void convert_x(const float* __restrict__ x,
                                                 ushort* __restrict__ xq) {
    const int n4 = (TSEQ * BATCH * HID) / 4;
    int stride = gridDim.x * blockDim.x;
    for (int i = blockIdx.x * blockDim.x + threadIdx.x; i < n4; i += stride) {
        float4 v = ((const float4*)x)[i];
        ushort4 o;
        o.x = f32_to_bf16(v.x);
        o.y = f32_to_bf16(v.y);
        o.z = f32_to_bf16(v.z);
        o.w = f32_to_bf16(v.w);
        ((ushort4*)xq)[i] = o;
    }
}

// ---- transpose+convert weights: WT[m][n][k] = W[k][n], m: 0=Wx0 1=Wh0 2=Wx1 3=Wh1 ----
__global__ __launch_bounds__(256) void transpose_w(const float* __restrict__ Wh,
                                                   const float* __restrict__ Wx,
                                                   ushort* __restrict__ WT) {
    int bid = blockIdx.x;            // 4 * 8 * 32 = 1024 blocks
    int m  = bid >> 8;               // 0..3
    int kt = (bid >> 5) & 7;         // k tile (64)
    int nt = bid & 31;               // n tile (64)
    const float* src = ((m & 1) ? Wh : Wx) + (size_t)(m >> 1) * (HID * H4);

    __shared__ float tile[64][65];
    int c  = threadIdx.x & 63;
    int r0 = (threadIdx.x >> 6) * 16;
    for (int i = 0; i < 16; ++i) {
        int r = r0 + i;
        tile[r][c] = src[(size_t)(kt * 64 + r) * H4 + nt * 64 + c];
    }
    __syncthreads();
    int k  = threadIdx.x & 63;
    int n0 = (threadIdx.x >> 6) * 16;
    for (int i = 0; i < 16; ++i) {
        int n = n0 + i;
        WT[(size_t)m * (H4 * HID) + (size_t)(nt * 64 + n) * HID + kt * 64 + k] =
            f32_to_bf16(tile[k][n]);
    }
}

// ---- persistent LSTM kernel: 256 WGs x 512 threads ----
__global__ __launch_bounds__(512, 2) void lstm_persistent(
    const ushort* __restrict__ WT,   // [4][2048][512] bf16 (N-major, K contiguous)
    const ushort* __restrict__ xq,   // [512][64][512] bf16
    const float*  __restrict__ bh,   // [2][2048]
    ushort* __restrict__ h0r,        // [DEPTH+1][64][512] bf16 ring (+ zero slot)
    ushort* __restrict__ h1r,        // [DEPTH+1][64][512]
    float*  __restrict__ out,        // d_out
    int*    __restrict__ flags)      // [2][4][32] stage counters, zeroed
{
    const int wg    = blockIdx.x;        // 0..255
    const int layer = wg >> 7;
    const int quad  = (wg >> 5) & 3;
    const int strip = wg & 31;
    const int j0    = strip * 16;
    const int tid   = threadIdx.x;
    const int wave  = tid >> 6;          // 0..7
    const int lane  = tid & 63;
    const int g     = wave & 3;          // gate
    const int kh    = wave >> 2;         // K half (0..1)
    const int lo    = lane & 15;
    const int hi    = lane >> 4;

    // weight fragment base pointers (gemm_bt layout, k contiguous-8/lane)
    const ushort* bx = WT + (size_t)(layer * 2 + 0) * (H4 * HID)
                     + (size_t)(g * 512 + j0 + lo) * HID + kh * 256 + hi * 8;
    const ushort* bw = WT + (size_t)(layer * 2 + 1) * (H4 * HID)
                     + (size_t)(g * 512 + j0 + lo) * HID + kh * 256 + hi * 8;

    // gate-phase mapping (threads 0..127): row = tid>>3 (0..15), cols cp,cp+1
    const int grow = tid >> 3;
    const int cp   = (tid & 7) * 2;
    f32x2 bias2[4];
#pragma unroll
    for (int gg = 0; gg < 4; ++gg)
        bias2[gg] = *(const f32x2*)&bh[layer * H4 + gg * 512 + j0 + cp];
    f32x2 creg = (f32x2)(0.f);

    __shared__ __align__(16) ushort ldsA[2][QR * HID];     // 32 KB: A1, A2 tiles
    __shared__ __align__(16) float  lds_g[4][2][QR][18];   // padded

    // staging: 1024 16B-chunks per 16KB tile; this thread: (rowa,kba),(rowb,kba)
    const int rowa = tid >> 6;             // 0..7
    const int rowb = rowa + 8;             // 8..15
    const int kba  = tid & 63;
    const int goffa = (quad * QR + rowa) * HID + kba * 8;
    const int goffb = (quad * QR + rowb) * HID + kba * 8;
    const int laddra = ((rowa << 10) + (kba << 4)) ^ ((rowa & 7) << 4);
    const int laddrb = ((rowb << 10) + (kba << 4)) ^ ((rowb & 7) << 4);

    int* myflag = &flags[layer * 128 + quad * 32 + strip];
    const int* selfflags  = &flags[layer * 128 + quad * 32];
    const int* otherflags = &flags[(1 - layer) * 128 + quad * 32];

    for (int s = 0; s < TSEQ + 2; ++s) {
        const int t = s - 2 * layer;             // L0: t=s, L1: t=s-2
        const bool act = (t >= 0) && (t < TSEQ);

        if (act) {
            // ================= phase A: non-critical operand =================
            bf16x8 v0, v1;
            if (layer == 0) {
                const ushort* A1 = xq + (size_t)t * BH;       // static, cached
                v0 = *(const bf16x8*)(A1 + goffa);
                v1 = *(const bf16x8*)(A1 + goffb);
                // ring anti-dep: L1 must be past stage s-6 before we overwrite
                const int thr0 = s - (DEPTH - 3);             // s-5
                if (thr0 > 0) {
                    if (tid < 32)
                        while (__hip_atomic_load(&otherflags[tid], __ATOMIC_RELAXED,
                                                 __HIP_MEMORY_SCOPE_AGENT) < thr0) { }
                    // rendezvous happens at the sync after the LDS write below
                }
            } else {
                // h0[t] has one full stage of slack: poll rarely blocks
                const int thr0 = s - 1;
                if (tid < 32)
                    while (__hip_atomic_load(&otherflags[tid], __ATOMIC_RELAXED,
                                             __HIP_MEMORY_SCOPE_AGENT) < thr0) { }
                __syncthreads();                               // gate the sc1 loads
                const ushort* A1 = h0r + (size_t)((s - 2) & (DEPTH - 1)) * BH;
                v0 = load16_sc1(A1 + goffa);
                v1 = load16_sc1(A1 + goffb);
            }
            asm volatile("s_waitcnt vmcnt(0)" ::: "memory");
            __builtin_amdgcn_sched_barrier(0);
            *(bf16x8*)((char*)&ldsA[0][0] + laddra) = v0;
            *(bf16x8*)((char*)&ldsA[0][0] + laddrb) = v1;
            __syncthreads();

            f32x4 acc = (f32x4)(0.f);
#pragma unroll
            for (int kk = 0; kk < 8; ++kk) {                   // Wx-side MFMAs
                const int kb2 = kh * 512 + kk * 64 + hi * 16;
                const int ad  = ((lo << 10) + kb2) ^ ((lo & 7) << 4);
                bf16x8 a1  = *(const bf16x8*)((char*)&ldsA[0][0] + ad);
                bf16x8 wxf = *(const bf16x8*)(bx + kk * 32);
                acc = __builtin_amdgcn_mfma_f32_16x16x32_bf16(a1, wxf, acc, 0, 0, 0);
            }

            // ============ phase B: self-recurrence (critical chain) ==========
            if (t > 0) {
                if (tid < 32)
                    while (__hip_atomic_load(&selfflags[tid], __ATOMIC_RELAXED,
                                             __HIP_MEMORY_SCOPE_AGENT) < s) { }
                __syncthreads();
            }
            const ushort* A2;
            if (t == 0)
                A2 = (layer ? h1r : h0r) + (size_t)ZSLOT * BH;
            else
                A2 = layer ? (h1r + (size_t)((s - 3) & (DEPTH - 1)) * BH)
                           : (h0r + (size_t)((s - 1) & (DEPTH - 1)) * BH);
            bf16x8 v2 = load16_sc1(A2 + goffa);
            bf16x8 v3 = load16_sc1(A2 + goffb);
            asm volatile("s_waitcnt vmcnt(0)" ::: "memory");
            __builtin_amdgcn_sched_barrier(0);
            *(bf16x8*)((char*)&ldsA[1][0] + laddra) = v2;
            *(bf16x8*)((char*)&ldsA[1][0] + laddrb) = v3;
            __syncthreads();

#pragma unroll
            for (int kk = 0; kk < 8; ++kk) {                   // Wh-side MFMAs
                const int kb2 = kh * 512 + kk * 64 + hi * 16;
                const int ad  = ((lo << 10) + kb2) ^ ((lo & 7) << 4);
                bf16x8 a2  = *(const bf16x8*)((char*)&ldsA[1][0] + ad);
                bf16x8 whf = *(const bf16x8*)(bw + kk * 32);
                acc = __builtin_amdgcn_mfma_f32_16x16x32_bf16(a2, whf, acc, 0, 0, 0);
            }
            // C/D layout: col = lane&15 (gate col), row = (lane>>4)*4 + r
#pragma unroll
            for (int r = 0; r < 4; ++r)
                lds_g[g][kh][hi * 4 + r][lo] = acc[r];
            __syncthreads();

            // ---- gates (2 waves): 2 cells per thread ----
            f32x2 cn, hn;
            if (tid < 128) {
                f32x2 gi = *(const f32x2*)&lds_g[0][0][grow][cp]
                         + *(const f32x2*)&lds_g[0][1][grow][cp] + bias2[0];
                f32x2 gf = *(const f32x2*)&lds_g[1][0][grow][cp]
                         + *(const f32x2*)&lds_g[1][1][grow][cp] + bias2[1];
                f32x2 gg = *(const f32x2*)&lds_g[2][0][grow][cp]
                         + *(const f32x2*)&lds_g[2][1][grow][cp] + bias2[2];
                f32x2 go = *(const f32x2*)&lds_g[3][0][grow][cp]
                         + *(const f32x2*)&lds_g[3][1][grow][cp] + bias2[3];
#pragma unroll
                for (int q = 0; q < 2; ++q) {
                    float si = 1.f / (1.f + __expf(-gi[q]));
                    float sf = 1.f / (1.f + __expf(-gf[q]));
                    float so = 1.f / (1.f + __expf(-go[q]));
                    float tg = tanhf(gg[q]);
                    cn[q] = sf * creg[q] + si * tg;
                    hn[q] = so * tanhf(cn[q]);
                }
                creg = cn;

                // publish h (sc1, 2 bf16 packed), drain this wave's stores
                ushort* hw = ((layer == 0) ? h0r : h1r)
                           + (size_t)(t & (DEPTH - 1)) * BH
                           + (size_t)(quad * QR + grow) * HID + j0 + cp;
                unsigned hp = (unsigned)f32_to_bf16(hn[0])
                            | ((unsigned)f32_to_bf16(hn[1]) << 16);
                __hip_atomic_store((unsigned*)hw, hp, __ATOMIC_RELAXED,
                                   __HIP_MEMORY_SCOPE_AGENT);
                asm volatile("s_waitcnt vmcnt(0)" ::: "memory");
            }
            __syncthreads();          // gate waves drained -> flag is safe
            if (tid == 0)
                __hip_atomic_store(myflag, s + 1, __ATOMIC_RELAXED,
                                   __HIP_MEMORY_SCOPE_AGENT);
            // out / finals AFTER the flag (off the critical path)
            if (tid < 128) {
                if (layer == 1)
                    *(f32x2*)&out[(size_t)t * BH + (size_t)(quad * QR + grow) * HID
                                  + j0 + cp] = hn;
                if (t == TSEQ - 1) {
                    size_t base = (size_t)TSEQ * BH + (size_t)layer * BH
                                + (size_t)(quad * QR + grow) * HID + j0 + cp;
                    *(f32x2*)&out[base] = hn;                       // h_fin
                    *(f32x2*)&out[base + 2 * (size_t)BH] = cn;      // c_fin
                }
            }
        } else {
            // inactive stage still publishes (consumers rely on monotone flags)
            if (tid == 0)
                __hip_atomic_store(myflag, s + 1, __ATOMIC_RELAXED,
                                   __HIP_MEMORY_SCOPE_AGENT);
        }
    }
}

extern "C" void kernel_launch(void* const* d_in, const int* in_sizes, int n_in,
                              void* d_out, int out_size, void* d_ws, size_t ws_size,
                              hipStream_t stream) {
    const float* x  = (const float*)d_in[0];
    const float* Wh = (const float*)d_in[1];
    const float* Wx = (const float*)d_in[2];
    const float* bh = (const float*)d_in[3];
    float* out = (float*)d_out;

    char* ws = (char*)d_ws;
    // layout: WT 8MB | xq 32MB | h0r | h1r | flags   (~41.2MB total)
    ushort* WT = (ushort*)ws;
    ushort* xq = (ushort*)(ws + ((size_t)8 << 20));
    char* state = ws + ((size_t)8 << 20) + ((size_t)32 << 20);
    ushort* h0r = (ushort*)state;                          // [DEPTH+1][64][512]
    ushort* h1r = h0r + (size_t)(DEPTH + 1) * BH;
    int* flags  = (int*)(h1r + (size_t)(DEPTH + 1) * BH);  // [2][4][32]
    size_t clear_bytes = (size_t)2 * (DEPTH + 1) * BH * sizeof(ushort) + 256 * sizeof(int);

    hipMemsetAsync(state, 0, clear_bytes, stream);  // zero rings + zero-slots + flags
    convert_x<<<2048, 256, 0, stream>>>(x, xq);
    transpose_w<<<1024, 256, 0, stream>>>(Wh, Wx, WT);
    lstm_persistent<<<256, 512, 0, stream>>>(WT, xq, bh, h0r, h1r, out, flags);
}